// Round 10
// baseline (130.083 us; speedup 1.0000x reference)
//
#include <hip/hip_runtime.h>
#include <hip/hip_bf16.h>

// B=8, C=64, O=64, H=W=128, stride=1, pad=1, 3x3.
constexpr int Bc = 8;
constexpr int Cc = 64;
constexpr int Oc = 64;
constexpr int Hc = 128;
constexpr int Wc = 128;
constexpr int HWc = Hc * Wc;

typedef __attribute__((ext_vector_type(8))) short short8;   // 8 x bf16
typedef __attribute__((ext_vector_type(4))) float floatx4;
typedef __attribute__((ext_vector_type(2))) float floatx2;
typedef __attribute__((ext_vector_type(4))) unsigned uintx4;

__device__ __forceinline__ float bperm(int idx4, float v) {
    return __int_as_float(__builtin_amdgcn_ds_bpermute(idx4, __float_as_int(v)));
}
// packed f32x2 -> bf16x2 (RNE), lo -> bits[15:0]
__device__ __forceinline__ unsigned cvt_pk_bf16(float lo, float hi) {
    unsigned r;
    asm("v_cvt_pk_bf16_f32 %0, %1, %2" : "=v"(r) : "v"(lo), "v"(hi));
    return r;
}

// v10: v9's two-kernel split WITHOUT d_ws (v9 post-mortem: using d_ws likely
// triggered a ~42us per-iteration workspace re-poison; kernels themselves may
// have been ~10us total). sel is staged INSIDE d_out:
//   sel for row h of image b lives in the exact byte write-set of K2 block
//   (b,h): fragments at out[b] float-offset g*16384 + h*128 + (w&3)*32,
//   g = w>>2 (stripes o=0..31, 512B per fragment of 4 pixels x 64ch bf16).
// Safety: blocks of different h use disjoint 512B slots of each 64KB o-stripe;
// different images disjoint 4MB regions; K1->K2 ordered by dispatch boundary.
// K2 preloads ALL 16 B-fragments to regs, __syncthreads (drains vmcnt), THEN
// stores - so a block only overwrites sel bytes it alone owns, after reading.
// Out is fully overwritten by K2. Math identical to v9 (passed).
__global__ __launch_bounds__(256, 4) void sel_kernel(
    const float* __restrict__ x, const float* __restrict__ peri,
    const float* __restrict__ thr, const float* __restrict__ scl,
    float* out)
{
    __shared__ float s_divp[4][Wc];             // 2048 B (only LDS)

    const int tid = threadIdx.x;
    const int l   = tid & 63;                   // lane
    const int wv  = tid >> 6;                   // wave 0..3
    const int b   = blockIdx.x & 7;             // one image per XCD
    const int h   = blockIdx.x >> 3;            // row 0..127
    const int c0  = wv * 16;                    // wave's 16 channels

    const int upIdx = ((l - 1) & 63) << 2;      // bperm byte idx: lane l-1
    const int dnIdx = ((l + 1) & 63) << 2;      // lane l+1
    const float lzf = (l == 0)  ? 0.f : 1.f;    // w=0 left pad
    const float rzf = (l == 63) ? 0.f : 1.f;    // w=127 right pad
    const float mUf = (h > 0) ? 1.f : 0.f;
    const float mDf = (h < Hc - 1) ? 1.f : 0.f;
    const int   dU  = (h > 0) ? -Wc : 0;        // clamped row offsets
    const int   dD  = (h < Hc - 1) ? Wc : 0;

    const float p0 = peri[0], p1 = peri[1], p2 = peri[2], p3 = peri[3];
    const float p4 = peri[4], p5 = peri[5], p6 = peri[6], p7 = peri[7];
    const float thrv = thr[0], sclv = scl[0];

    const float* xw = x + (size_t)b * Cc * HWc + (size_t)h * Wc + 2 * l;

    float dlo = 0.f, dhi = 0.f;
    unsigned aggLoPk[8], aggHiPk[8], cenLoPk[8], cenHiPk[8];

// One channel: RM/R0/R1 = rows h-1,h,h+1 (vert pre-masked), K = slot in pair.
#define PROC1(RM, R0, R1, K) do {                                             \
    const float rmL = lzf * bperm(upIdx, RM.y);                               \
    const float r0L = lzf * bperm(upIdx, R0.y);                               \
    const float r1L = lzf * bperm(upIdx, R1.y);                               \
    const float rmR = rzf * bperm(dnIdx, RM.x);                               \
    const float r0R = rzf * bperm(dnIdx, R0.x);                               \
    const float r1R = rzf * bperm(dnIdx, R1.x);                               \
    { const float t = R0.x;  /* pixel lo (w=2l) */                            \
      float a = p0 * rmL; a = fmaf(p1, RM.x, a); a = fmaf(p2, RM.y, a);       \
      a = fmaf(p3, r0L, a); a = fmaf(p4, R0.y, a);                            \
      a = fmaf(p5, r1L, a); a = fmaf(p6, R1.x, a); a = fmaf(p7, R1.y, a);     \
      aLo[K] = a; float e;                                                    \
      e = rmL  - t; dlo = fmaf(e, e, dlo); e = RM.x - t; dlo = fmaf(e, e, dlo); \
      e = RM.y - t; dlo = fmaf(e, e, dlo); e = r0L  - t; dlo = fmaf(e, e, dlo); \
      e = R0.y - t; dlo = fmaf(e, e, dlo); e = r1L  - t; dlo = fmaf(e, e, dlo); \
      e = R1.x - t; dlo = fmaf(e, e, dlo); e = R1.y - t; dlo = fmaf(e, e, dlo); } \
    { const float t = R0.y;  /* pixel hi (w=2l+1) */                          \
      float a = p0 * RM.x; a = fmaf(p1, RM.y, a); a = fmaf(p2, rmR, a);       \
      a = fmaf(p3, R0.x, a); a = fmaf(p4, r0R, a);                            \
      a = fmaf(p5, R1.x, a); a = fmaf(p6, R1.y, a); a = fmaf(p7, r1R, a);     \
      aHi[K] = a; float e;                                                    \
      e = RM.x - t; dhi = fmaf(e, e, dhi); e = RM.y - t; dhi = fmaf(e, e, dhi); \
      e = rmR  - t; dhi = fmaf(e, e, dhi); e = R0.x - t; dhi = fmaf(e, e, dhi); \
      e = r0R  - t; dhi = fmaf(e, e, dhi); e = R1.x - t; dhi = fmaf(e, e, dhi); \
      e = R1.y - t; dhi = fmaf(e, e, dhi); e = r1R  - t; dhi = fmaf(e, e, dhi); } \
} while (0)

    #pragma unroll 2
    for (int j = 0; j < 8; ++j) {               // 8 channel pairs = 16 ch
        const int cA = c0 + 2 * j;
        const float* b0p = xw + (size_t)cA * HWc;
        const float* b1p = b0p + HWc;

        floatx2 rm0 = *(const floatx2*)(b0p + dU);
        floatx2 r00 = *(const floatx2*)(b0p);
        floatx2 r10 = *(const floatx2*)(b0p + dD);
        floatx2 rm1 = *(const floatx2*)(b1p + dU);
        floatx2 r01 = *(const floatx2*)(b1p);
        floatx2 r11 = *(const floatx2*)(b1p + dD);
        rm0 *= mUf; r10 *= mDf; rm1 *= mUf; r11 *= mDf;   // zero padded rows

        float aLo[2], aHi[2];
        PROC1(rm0, r00, r10, 0);
        PROC1(rm1, r01, r11, 1);

        // pack agg + center as bf16 pairs (c, c+1) for both pixels
        aggLoPk[j] = cvt_pk_bf16(aLo[0], aLo[1]);
        aggHiPk[j] = cvt_pk_bf16(aHi[0], aHi[1]);
        cenLoPk[j] = cvt_pk_bf16(r00.x, r01.x);
        cenHiPk[j] = cvt_pk_bf16(r00.y, r01.y);
    }
#undef PROC1

    {   floatx2 dv = {dlo, dhi};
        *(floatx2*)&s_divp[wv][2 * l] = dv;
    }
    __syncthreads();                            // the ONLY barrier

    // per-pixel div over all 64 channels; unconditional packed select
    floatx2 sum2 = {0.f, 0.f};
    #pragma unroll
    for (int g = 0; g < 4; ++g)
        sum2 += *(const floatx2*)&s_divp[g][2 * l];
    const bool oneLo = ((sum2.x - thrv) * sclv) > 0.f;   // == sigmoid>0.5
    const bool oneHi = ((sum2.y - thrv) * sclv) > 0.f;

    uintx4 sLo0, sLo1, sHi0, sHi1;
    #pragma unroll
    for (int i = 0; i < 4; ++i) {
        sLo0[i] = oneLo ? aggLoPk[i]     : cenLoPk[i];
        sLo1[i] = oneLo ? aggLoPk[i + 4] : cenLoPk[i + 4];
        sHi0[i] = oneHi ? aggHiPk[i]     : cenHiPk[i];
        sHi1[i] = oneHi ? aggHiPk[i + 4] : cenHiPk[i + 4];
    }

    // sel -> out-scratch, inside block (b,h)'s future K2 write-set:
    // pixel w, ch [c0,c0+16): float-off (w>>2)*16384 + h*128 + (w&3)*32 + wv*8
    float* ob = out + (size_t)b * Oc * HWc;
    const int g  = l >> 1;                      // both px share stripe g
    const int u0 = 2 * (l & 1);                 // px 2l -> u0, px 2l+1 -> u0+1
    float* plo = ob + g * 16384 + h * 128 + u0 * 32 + wv * 8;
    *(uintx4*)(plo)      = sLo0;                // px 2l,   ch c0..c0+7
    *(uintx4*)(plo + 4)  = sLo1;                // px 2l,   ch c0+8..c0+15
    *(uintx4*)(plo + 32) = sHi0;                // px 2l+1, ch c0..c0+7
    *(uintx4*)(plo + 36) = sHi1;                // px 2l+1, ch c0+8..c0+15
}

// K2: out[b][o][p] = sum_c core[o][c] * sel[c][p], sel read from out-scratch.
// Preload all B-frags -> regs, barrier (drains vmcnt), then MFMA + overwrite.
__global__ __launch_bounds__(256, 4) void gemm_kernel(
    const float* __restrict__ core, float* out)
{
    const int tid = threadIdx.x;
    const int l   = tid & 63;
    const int wv  = tid >> 6;                   // wave 0..3
    const int b   = blockIdx.x & 7;             // same XCD as producer
    const int h   = blockIdx.x >> 3;            // row 0..127

    const int o0   = wv * 16;                   // wave's o-tile
    const int n    = l & 15;
    const int quad = l >> 4;

    // A-fragments: core[o0+n][k], k = quad*8+j (A0: k 0..31, A1: k 32..63)
    const float* arow = core + (size_t)(o0 + n) * Cc + quad * 8;
    const floatx4 af0 = *(const floatx4*)(arow);
    const floatx4 af1 = *(const floatx4*)(arow + 4);
    const floatx4 af2 = *(const floatx4*)(arow + 32);
    const floatx4 af3 = *(const floatx4*)(arow + 36);

    float* ob = out + (size_t)b * Oc * HWc;

    // preload ALL 16 B-fragments (sel lives in this block's own write-set)
    short8 Bf0[8], Bf1[8];                      // static idx via full unroll
    #pragma unroll
    for (int t = 0; t < 8; ++t) {
        const int w = t * 16 + n, g = w >> 2, u = w & 3;
        const float* fp = ob + g * 16384 + h * 128 + u * 32 + quad * 4;
        Bf0[t] = *(const short8*)(fp);          // ch quad*8 .. +7
        Bf1[t] = *(const short8*)(fp + 16);     // ch 32+quad*8 .. +7
    }

    union { unsigned u[4]; short8 s; } A0, A1;
    A0.u[0] = cvt_pk_bf16(af0.x, af0.y); A0.u[1] = cvt_pk_bf16(af0.z, af0.w);
    A0.u[2] = cvt_pk_bf16(af1.x, af1.y); A0.u[3] = cvt_pk_bf16(af1.z, af1.w);
    A1.u[0] = cvt_pk_bf16(af2.x, af2.y); A1.u[1] = cvt_pk_bf16(af2.z, af2.w);
    A1.u[2] = cvt_pk_bf16(af3.x, af3.y); A1.u[3] = cvt_pk_bf16(af3.z, af3.w);

    __syncthreads();   // vmcnt drained in all waves: every B-frag is in regs

    #pragma unroll
    for (int t = 0; t < 8; ++t) {
        floatx4 acc = {0.f, 0.f, 0.f, 0.f};
        acc = __builtin_amdgcn_mfma_f32_16x16x32_bf16(A0.s, Bf0[t], acc, 0, 0, 0);
        acc = __builtin_amdgcn_mfma_f32_16x16x32_bf16(A1.s, Bf1[t], acc, 0, 0, 0);
        #pragma unroll
        for (int r = 0; r < 4; ++r) {
            const int o = o0 + quad * 4 + r;
            ob[(size_t)o * HWc + h * Wc + t * 16 + n] = acc[r];
        }
    }
}

extern "C" void kernel_launch(void* const* d_in, const int* in_sizes, int n_in,
                              void* d_out, int out_size, void* d_ws, size_t ws_size,
                              hipStream_t stream) {
    const float* x    = (const float*)d_in[0];
    const float* core = (const float*)d_in[1];
    const float* peri = (const float*)d_in[2];
    const float* thr  = (const float*)d_in[3];
    const float* scl  = (const float*)d_in[4];
    float* out = (float*)d_out;

    sel_kernel<<<dim3(Bc * Hc), dim3(256), 0, stream>>>(
        x, peri, thr, scl, out);
    gemm_kernel<<<dim3(Bc * Hc), dim3(256), 0, stream>>>(core, out);
}

// Round 11
// 124.950 us; speedup vs baseline: 1.0411x; 1.0411x over previous
//
#include <hip/hip_runtime.h>
#include <hip/hip_bf16.h>

// B=8, C=64, O=64, H=W=128, stride=1, pad=1, 3x3.
constexpr int Bc = 8;
constexpr int Cc = 64;
constexpr int Oc = 64;
constexpr int Hc = 128;
constexpr int Wc = 128;
constexpr int HWc = Hc * Wc;

typedef __attribute__((ext_vector_type(8))) short short8;   // 8 x bf16
typedef __attribute__((ext_vector_type(4))) float floatx4;
typedef __attribute__((ext_vector_type(2))) float floatx2;
typedef __attribute__((ext_vector_type(4))) unsigned uintx4;

// packed f32x2 -> bf16x2 (RNE), lo -> bits[15:0]
__device__ __forceinline__ unsigned cvt_pk_bf16(float lo, float hi) {
    unsigned r;
    asm("v_cvt_pk_bf16_f32 %0, %1, %2" : "=v"(r) : "v"(lo), "v"(hi));
    return r;
}

// v11: WAVE-AUTONOMOUS. Ten-round evidence: every variant keeping the
// barrier + LDS fragment-transpose pinned at 22-24.5us; global-split worse.
// The transpose IS the convoy. Here each lane computes sel directly in
// MFMA B-fragment layout: lane (n,quad) of a 16-px tile handles pixel
// w0+n, channels {quad*8..+7} u {32+quad*8..+7} (exactly its B-fragment
// slots). Taps: aligned float2 + 1 dword per row, parity-resolved with
// lane-constant cndmasks. div: partial over lane's 16 ch, completed by
// __shfl_xor(16)+__shfl_xor(32) across the 4 quads (bit-identical sums).
// Mask-select in regs -> B-fragment born in-register.
// ZERO LDS, ZERO barriers, ZERO transpose. Waves fully independent ->
// 16 waves/CU of real TLP. 8 MFMAs/wave (4 o-tiles x K=64), 16 stores/lane.
// XCD remap kept (b = blk&7, h ascending per XCD).
__global__ __launch_bounds__(256, 4) void spconv_kernel(
    const float* __restrict__ x, const float* __restrict__ core,
    const float* __restrict__ peri, const float* __restrict__ thr,
    const float* __restrict__ scl, float* __restrict__ out)
{
    const int tid  = threadIdx.x;
    const int l    = tid & 63;                  // lane
    const int wv   = tid >> 6;                  // wave 0..3
    const int b    = blockIdx.x & 7;            // one image per XCD
    const int rh   = blockIdx.x >> 3;           // 0..255
    const int h    = rh >> 1;                   // row 0..127
    const int half = rh & 1;                    // row half
    const int n    = l & 15;
    const int quad = l >> 4;
    const int w0   = half * 64 + wv * 16;       // tile base
    const int wpix = w0 + n;                    // this lane's pixel

    // lane-constant horizontal geometry
    const int  w2 = wpix & ~1;                  // aligned f2 base
    const bool ep = (wpix & 1) != 0;            // parity
    const bool lm = wpix > 0;
    const bool rm = wpix < Wc - 1;
    const int  eoff = ep ? (rm ? wpix + 1 : wpix) : (lm ? wpix - 1 : 0);

    // block-uniform vertical geometry
    const float mUf = (h > 0) ? 1.f : 0.f;
    const float mDf = (h < Hc - 1) ? 1.f : 0.f;
    const int   dU  = (h > 0) ? -Wc : 0;
    const int   dD  = (h < Hc - 1) ? Wc : 0;

    const float p0 = peri[0], p1 = peri[1], p2 = peri[2], p3 = peri[3];
    const float p4 = peri[4], p5 = peri[5], p6 = peri[6], p7 = peri[7];
    const float thrv = thr[0], sclv = scl[0];

    const float* rp0 = x + (size_t)b * Cc * HWc + (size_t)h * Wc;

    float dacc = 0.f;
    unsigned aggPk[8], cenPk[8];   // [0..3] = ch quad*8.., [4..7] = 32+quad*8..

// One channel CIDX: 6 loads (3 aligned f2 + 3 dword), lane-constant selects,
// agg (8 fma), center, div partial (8 sub+fma). Padded taps value-zeroed.
#define PROCC(CIDX, AGGV, CENV) do {                                          \
    const float* rp = rp0 + (size_t)(CIDX) * HWc;                             \
    const floatx2 vU = *(const floatx2*)(rp + dU + w2);                       \
    const floatx2 vC = *(const floatx2*)(rp + w2);                            \
    const floatx2 vD = *(const floatx2*)(rp + dD + w2);                       \
    const float eU = rp[dU + eoff];                                           \
    const float eC = rp[eoff];                                                \
    const float eD = rp[dD + eoff];                                           \
    const float uL = (ep ? vU.x : (lm ? eU : 0.f)) * mUf;                     \
    const float uC = (ep ? vU.y : vU.x) * mUf;                                \
    const float uR = (ep ? (rm ? eU : 0.f) : vU.y) * mUf;                     \
    const float cL =  ep ? vC.x : (lm ? eC : 0.f);                            \
    const float t  =  ep ? vC.y : vC.x;                                       \
    const float cR =  ep ? (rm ? eC : 0.f) : vC.y;                            \
    const float dL = (ep ? vD.x : (lm ? eD : 0.f)) * mDf;                     \
    const float dC = (ep ? vD.y : vD.x) * mDf;                                \
    const float dR = (ep ? (rm ? eD : 0.f) : vD.y) * mDf;                     \
    float a = p0 * uL; a = fmaf(p1, uC, a); a = fmaf(p2, uR, a);              \
    a = fmaf(p3, cL, a); a = fmaf(p4, cR, a);                                 \
    a = fmaf(p5, dL, a); a = fmaf(p6, dC, a); a = fmaf(p7, dR, a);            \
    AGGV = a; CENV = t;                                                       \
    float e;                                                                  \
    e = uL - t; dacc = fmaf(e, e, dacc); e = uC - t; dacc = fmaf(e, e, dacc); \
    e = uR - t; dacc = fmaf(e, e, dacc); e = cL - t; dacc = fmaf(e, e, dacc); \
    e = cR - t; dacc = fmaf(e, e, dacc); e = dL - t; dacc = fmaf(e, e, dacc); \
    e = dC - t; dacc = fmaf(e, e, dacc); e = dR - t; dacc = fmaf(e, e, dacc); \
} while (0)

    const int cb = quad * 8;
    #pragma unroll
    for (int hf = 0; hf < 2; ++hf) {            // K-halves: ch cb.., 32+cb..
        const int cbase = hf * 32 + cb;
        #pragma unroll
        for (int jp = 0; jp < 4; ++jp) {        // channel pairs
            float a0, c0v, a1, c1v;
            PROCC(cbase + 2 * jp,     a0, c0v);
            PROCC(cbase + 2 * jp + 1, a1, c1v);
            aggPk[hf * 4 + jp] = cvt_pk_bf16(a0, a1);
            cenPk[hf * 4 + jp] = cvt_pk_bf16(c0v, c1v);
        }
    }
#undef PROCC

    // complete div over all 64 ch: butterfly across the 4 quads (same pixel).
    // xor16/xor32 sums are bit-identical on all 4 lanes -> uniform mask.
    dacc += __shfl_xor(dacc, 16);
    dacc += __shfl_xor(dacc, 32);
    const bool one = ((dacc - thrv) * sclv) > 0.f;   // == sigmoid>0.5

    // B-fragments born in-register
    union { unsigned u[4]; short8 s; } B0, B1;
    #pragma unroll
    for (int i = 0; i < 4; ++i) {
        B0.u[i] = one ? aggPk[i]     : cenPk[i];
        B1.u[i] = one ? aggPk[i + 4] : cenPk[i + 4];
    }

    // A-fragments: core[o0+n][k], k = quad*8+j and 32+quad*8+j; L2-hot 16KB
    union { unsigned u[4]; short8 s; } A0[4], A1[4];
    #pragma unroll
    for (int ot = 0; ot < 4; ++ot) {
        const float* ar = core + (size_t)(ot * 16 + n) * Cc + cb;
        const floatx4 f0 = *(const floatx4*)(ar);
        const floatx4 f1 = *(const floatx4*)(ar + 4);
        const floatx4 f2 = *(const floatx4*)(ar + 32);
        const floatx4 f3 = *(const floatx4*)(ar + 36);
        A0[ot].u[0] = cvt_pk_bf16(f0.x, f0.y); A0[ot].u[1] = cvt_pk_bf16(f0.z, f0.w);
        A0[ot].u[2] = cvt_pk_bf16(f1.x, f1.y); A0[ot].u[3] = cvt_pk_bf16(f1.z, f1.w);
        A1[ot].u[0] = cvt_pk_bf16(f2.x, f2.y); A1[ot].u[1] = cvt_pk_bf16(f2.z, f2.w);
        A1[ot].u[2] = cvt_pk_bf16(f3.x, f3.y); A1[ot].u[3] = cvt_pk_bf16(f3.z, f3.w);
    }

    // GEMM: 4 o-tiles x (2 MFMA, K=64); D col = n (pixel), row = quad*4+r (o)
    float* outb = out + (size_t)b * Oc * HWc + (size_t)h * Wc + wpix;
    #pragma unroll
    for (int ot = 0; ot < 4; ++ot) {
        floatx4 acc = {0.f, 0.f, 0.f, 0.f};
        acc = __builtin_amdgcn_mfma_f32_16x16x32_bf16(A0[ot].s, B0.s, acc, 0, 0, 0);
        acc = __builtin_amdgcn_mfma_f32_16x16x32_bf16(A1[ot].s, B1.s, acc, 0, 0, 0);
        #pragma unroll
        for (int r = 0; r < 4; ++r) {
            const int o = ot * 16 + quad * 4 + r;
            outb[(size_t)o * HWc] = acc[r];
            // note: column offset wpix already folded into outb
        }
        // advance nothing: o encoded per store above
    }
}

extern "C" void kernel_launch(void* const* d_in, const int* in_sizes, int n_in,
                              void* d_out, int out_size, void* d_ws, size_t ws_size,
                              hipStream_t stream) {
    const float* x    = (const float*)d_in[0];
    const float* core = (const float*)d_in[1];
    const float* peri = (const float*)d_in[2];
    const float* thr  = (const float*)d_in[3];
    const float* scl  = (const float*)d_in[4];
    float* out = (float*)d_out;

    spconv_kernel<<<dim3(Bc * Hc * 2), dim3(256), 0, stream>>>(
        x, core, peri, thr, scl, out);
}

// Round 12
// 96.606 us; speedup vs baseline: 1.3465x; 1.2934x over previous
//
#include <hip/hip_runtime.h>
#include <hip/hip_bf16.h>

// B=8, C=64, O=64, H=W=128, stride=1, pad=1, 3x3.
constexpr int Bc = 8;
constexpr int Cc = 64;
constexpr int Oc = 64;
constexpr int Hc = 128;
constexpr int Wc = 128;
constexpr int HWc = Hc * Wc;
constexpr int CP = 72;   // padded LDS row stride bf16 (144 B = 16B-aligned)

typedef __attribute__((ext_vector_type(8))) short short8;   // 8 x bf16
typedef __attribute__((ext_vector_type(4))) float floatx4;
typedef __attribute__((ext_vector_type(2))) float floatx2;

__device__ __forceinline__ float bperm(int idx4, float v) {
    return __int_as_float(__builtin_amdgcn_ds_bpermute(idx4, __float_as_int(v)));
}
// packed f32x2 -> bf16x2 (RNE), lo -> bits[15:0]
__device__ __forceinline__ unsigned cvt_pk_bf16(float lo, float hi) {
    unsigned r;
    asm("v_cvt_pk_bf16_f32 %0, %1, %2" : "=v"(r) : "v"(lo), "v"(hi));
    return r;
}

// FINAL (= round-4 v5, the measured best: 98.17us bench, kernel ~22us).
// Session summary for future readers:
//  - Structure: 2 output rows per block, 512 thr; lane owns pixel pair
//    (2l,2l+1) via float2 loads + ds_bpermute horizontal taps; packed
//    cvt_pk_bf16 LDS writes in w-parity-split physical rows; MFMA GEMM
//    (16x16x32 bf16, K=64) straight from LDS B-fragments.
//  - Measured wins kept: XCD remap (b=blk&7 -> FETCH 16.5MB < 32MB input),
//    s_any skip of the mask-fixup loop, bperm tap sharing, packed writes.
//  - Refuted alternatives (all slower or neutral): strip loads (v2 126),
//    load hoisting + single barrier (v6 99.3), 4 convoy-domains + setprio
//    (v7 99.8), persistent pipelined rows (v8 100.2), two-kernel split via
//    d_ws (v9 127.8) or out-scratch (v10 130.1), wave-autonomous in-register
//    B-fragments (v11 124.9: VGPR demotion to scratch + 3x VALU).
//  - Counters at plateau: no pipe saturated (VALU ~12%, HBM ~12%, MFMA ~1%);
//    residual is un-modeled latency; bench floor ~98 includes ~76us fixed
//    harness overhead (two 268MB poison fills).
__global__ __launch_bounds__(512, 4) void spconv_kernel(
    const float* __restrict__ x, const float* __restrict__ core,
    const float* __restrict__ peri, const float* __restrict__ thr,
    const float* __restrict__ scl, float* __restrict__ out)
{
    __shared__ __hip_bfloat16 s_selT[2][Wc][CP];  // [row][physw][c] 36864 B
    __shared__ __hip_bfloat16 s_core[Oc][CP];     //                  9216 B
    __shared__ float s_divp[2][8][Wc];            //                  8192 B
    __shared__ float s_msk[2][Wc];                //                  1024 B
    __shared__ int   s_any;

    const int tid = threadIdx.x;
    const int l   = tid & 63;                   // lane
    const int wv  = tid >> 6;                   // wave 0..7
    const int b   = blockIdx.x & 7;             // one image per XCD
    const int hp  = blockIdx.x >> 3;            // row pair 0..63
    const int h0  = hp * 2;

    if (tid == 0) s_any = 0;

    // ---- Phase 0: core -> bf16 LDS (float4 loads, packed writes) ----
    #pragma unroll
    for (int i = 0; i < 2; ++i) {
        const int idx = (i * 512 + tid) * 4;    // 4096 floats total
        const floatx4 v = *(const floatx4*)(core + idx);
        unsigned* dst = (unsigned*)&s_core[idx >> 6][idx & 63];
        dst[0] = cvt_pk_bf16(v.x, v.y);
        dst[1] = cvt_pk_bf16(v.z, v.w);
    }

    // ---- Phase 1: taps. Lane owns pixels w=2l,2l+1; wave owns 8 channels ----
    const int upIdx = ((l - 1) & 63) << 2;      // bperm byte index: lane l-1
    const int dnIdx = ((l + 1) & 63) << 2;      // lane l+1
    const float lzf = (l == 0)  ? 0.f : 1.f;    // w=0 left pad
    const float rzf = (l == 63) ? 0.f : 1.f;    // w=127 right pad
    const float mUf = (h0 > 0) ? 1.f : 0.f;
    const float mDf = (h0 < Hc - 2) ? 1.f : 0.f;
    const int   dU  = (h0 > 0) ? -Wc : 0;          // clamped row offsets
    const int   dD2 = (h0 < Hc - 2) ? 2 * Wc : Wc;

    const float p0 = peri[0], p1 = peri[1], p2 = peri[2], p3 = peri[3];
    const float p4 = peri[4], p5 = peri[5], p6 = peri[6], p7 = peri[7];

    const float* xw = x + (size_t)b * Cc * HWc + (size_t)h0 * Wc + 2 * l;
    const float* xb = x + (size_t)b * Cc * HWc + (size_t)h0 * Wc;  // fixup base

    float dAlo = 0.f, dAhi = 0.f, dBlo = 0.f, dBhi = 0.f;

// PROC: one channel. RM/R0/R1/R2 = rows h0-1..h0+2 (vert pre-masked), K = 0/1
// slot in the channel pair. Produces 4 agg values, accumulates 4 div sums.
#define PROC(RM, R0, R1, R2, K) do {                                          \
    const float rmL = lzf * bperm(upIdx, RM.y);                               \
    const float r0L = lzf * bperm(upIdx, R0.y);                               \
    const float r1L = lzf * bperm(upIdx, R1.y);                               \
    const float r2L = lzf * bperm(upIdx, R2.y);                               \
    const float rmR = rzf * bperm(dnIdx, RM.x);                               \
    const float r0R = rzf * bperm(dnIdx, R0.x);                               \
    const float r1R = rzf * bperm(dnIdx, R1.x);                               \
    const float r2R = rzf * bperm(dnIdx, R2.x);                               \
    { const float t = R0.x;  /* row A, pixel lo (w=2l) */                     \
      float a = p0 * rmL; a = fmaf(p1, RM.x, a); a = fmaf(p2, RM.y, a);       \
      a = fmaf(p3, r0L, a); a = fmaf(p4, R0.y, a);                            \
      a = fmaf(p5, r1L, a); a = fmaf(p6, R1.x, a); a = fmaf(p7, R1.y, a);     \
      aAlo[K] = a; float e;                                                   \
      e = rmL  - t; dAlo = fmaf(e, e, dAlo); e = RM.x - t; dAlo = fmaf(e, e, dAlo); \
      e = RM.y - t; dAlo = fmaf(e, e, dAlo); e = r0L  - t; dAlo = fmaf(e, e, dAlo); \
      e = R0.y - t; dAlo = fmaf(e, e, dAlo); e = r1L  - t; dAlo = fmaf(e, e, dAlo); \
      e = R1.x - t; dAlo = fmaf(e, e, dAlo); e = R1.y - t; dAlo = fmaf(e, e, dAlo); } \
    { const float t = R0.y;  /* row A, pixel hi (w=2l+1) */                   \
      float a = p0 * RM.x; a = fmaf(p1, RM.y, a); a = fmaf(p2, rmR, a);       \
      a = fmaf(p3, R0.x, a); a = fmaf(p4, r0R, a);                            \
      a = fmaf(p5, R1.x, a); a = fmaf(p6, R1.y, a); a = fmaf(p7, r1R, a);     \
      aAhi[K] = a; float e;                                                   \
      e = RM.x - t; dAhi = fmaf(e, e, dAhi); e = RM.y - t; dAhi = fmaf(e, e, dAhi); \
      e = rmR  - t; dAhi = fmaf(e, e, dAhi); e = R0.x - t; dAhi = fmaf(e, e, dAhi); \
      e = r0R  - t; dAhi = fmaf(e, e, dAhi); e = R1.x - t; dAhi = fmaf(e, e, dAhi); \
      e = R1.y - t; dAhi = fmaf(e, e, dAhi); e = r1R  - t; dAhi = fmaf(e, e, dAhi); } \
    { const float t = R1.x;  /* row B, pixel lo */                            \
      float a = p0 * r0L; a = fmaf(p1, R0.x, a); a = fmaf(p2, R0.y, a);       \
      a = fmaf(p3, r1L, a); a = fmaf(p4, R1.y, a);                            \
      a = fmaf(p5, r2L, a); a = fmaf(p6, R2.x, a); a = fmaf(p7, R2.y, a);     \
      aBlo[K] = a; float e;                                                   \
      e = r0L  - t; dBlo = fmaf(e, e, dBlo); e = R0.x - t; dBlo = fmaf(e, e, dBlo); \
      e = R0.y - t; dBlo = fmaf(e, e, dBlo); e = r1L  - t; dBlo = fmaf(e, e, dBlo); \
      e = R1.y - t; dBlo = fmaf(e, e, dBlo); e = r2L  - t; dBlo = fmaf(e, e, dBlo); \
      e = R2.x - t; dBlo = fmaf(e, e, dBlo); e = R2.y - t; dBlo = fmaf(e, e, dBlo); } \
    { const float t = R1.y;  /* row B, pixel hi */                            \
      float a = p0 * R0.x; a = fmaf(p1, R0.y, a); a = fmaf(p2, r0R, a);       \
      a = fmaf(p3, R1.x, a); a = fmaf(p4, r1R, a);                            \
      a = fmaf(p5, R2.x, a); a = fmaf(p6, R2.y, a); a = fmaf(p7, r2R, a);     \
      aBhi[K] = a; float e;                                                   \
      e = R0.x - t; dBhi = fmaf(e, e, dBhi); e = R0.y - t; dBhi = fmaf(e, e, dBhi); \
      e = r0R  - t; dBhi = fmaf(e, e, dBhi); e = R1.x - t; dBhi = fmaf(e, e, dBhi); \
      e = r1R  - t; dBhi = fmaf(e, e, dBhi); e = R2.x - t; dBhi = fmaf(e, e, dBhi); \
      e = R2.y - t; dBhi = fmaf(e, e, dBhi); e = r2R  - t; dBhi = fmaf(e, e, dBhi); } \
} while (0)

    #pragma unroll 2
    for (int j = 0; j < 4; ++j) {
        const int c0 = wv * 8 + 2 * j;          // channel pair c0, c0+1
        const float* b0p = xw + (size_t)c0 * HWc;
        const float* b1p = b0p + HWc;

        floatx2 rm0 = *(const floatx2*)(b0p + dU);
        floatx2 r00 = *(const floatx2*)(b0p);
        floatx2 r10 = *(const floatx2*)(b0p + Wc);
        floatx2 r20 = *(const floatx2*)(b0p + dD2);
        floatx2 rm1 = *(const floatx2*)(b1p + dU);
        floatx2 r01 = *(const floatx2*)(b1p);
        floatx2 r11 = *(const floatx2*)(b1p + Wc);
        floatx2 r21 = *(const floatx2*)(b1p + dD2);
        rm0 *= mUf; r20 *= mDf; rm1 *= mUf; r21 *= mDf;   // zero padded rows

        float aAlo[2], aAhi[2], aBlo[2], aBhi[2];
        PROC(rm0, r00, r10, r20, 0);
        PROC(rm1, r01, r11, r21, 1);

        // packed bf16x2 writes; phys rows: w=2l -> l, w=2l+1 -> 64+l
        *(unsigned*)&s_selT[0][l]      [c0] = cvt_pk_bf16(aAlo[0], aAlo[1]);
        *(unsigned*)&s_selT[0][64 + l] [c0] = cvt_pk_bf16(aAhi[0], aAhi[1]);
        *(unsigned*)&s_selT[1][l]      [c0] = cvt_pk_bf16(aBlo[0], aBlo[1]);
        *(unsigned*)&s_selT[1][64 + l] [c0] = cvt_pk_bf16(aBhi[0], aBhi[1]);
    }
#undef PROC

    {   // div partials (logical w indexing)
        floatx2 da = {dAlo, dAhi}, db = {dBlo, dBhi};
        *(floatx2*)&s_divp[0][wv][2 * l] = da;
        *(floatx2*)&s_divp[1][wv][2 * l] = db;
    }
    __syncthreads();

    // ---- A-fragments early (overlaps mask phase) ----
    const int o0   = (wv & 3) * 16;
    const int wh   = wv >> 2;
    const int n    = l & 15;
    const int quad = l >> 4;
    const short8 a0 = *(const short8*)&s_core[o0 + n][quad * 8];
    const short8 a1 = *(const short8*)&s_core[o0 + n][quad * 8 + 32];

    // ---- Phase 2: masks ----
    if (tid < 2 * Wc) {
        const int rr = tid >> 7, ww = tid & (Wc - 1);
        float dv = s_divp[rr][0][ww];
        #pragma unroll
        for (int g = 1; g < 8; ++g) dv += s_divp[rr][g][ww];
        const bool one = ((dv - thr[0]) * scl[0]) > 0.f;   // == sigmoid>0.5
        s_msk[rr][ww] = one ? 1.f : 0.f;
        if (!one) s_any = 1;              // benign race: all write 1
    }
    __syncthreads();

    // ---- Rare path: overwrite masked columns with center ----
    if (s_any) {                          // block-uniform branch
        #pragma unroll
        for (int i = 0; i < 32; ++i) {    // 2*8192 elems / 512 thr
            const int idx = i * 512 + tid;
            const int rr  = idx >> 13;
            const int e2  = idx & 8191;
            const int p   = e2 & (Wc - 1);                   // phys row
            const int c   = e2 >> 7;
            const int ww  = ((p & 63) << 1) | (p >> 6);      // logical w
            if (s_msk[rr][ww] == 0.f)
                s_selT[rr][p][c] =
                    __float2bfloat16(xb[(size_t)c * HWc + rr * Wc + ww]);
        }
        __syncthreads();
    }

    // ---- Phase 3: MFMA GEMM x2 rows: D[o][w] = core[o][c]*sel[c][w] ----
    float* outb = out + ((size_t)(b * Oc) * Hc + h0) * Wc;

    #pragma unroll
    for (int rr = 0; rr < 2; ++rr) {
        #pragma unroll
        for (int t = 0; t < 4; ++t) {
            const int w0   = (wh * 4 + t) * 16;
            const int wlog = w0 + n;
            const int pr   = ((wlog >> 1) & 63) | ((wlog & 1) << 6);
            const short8 b0 = *(const short8*)&s_selT[rr][pr][quad * 8];
            const short8 b1 = *(const short8*)&s_selT[rr][pr][quad * 8 + 32];
            floatx4 acc = {0.f, 0.f, 0.f, 0.f};
            acc = __builtin_amdgcn_mfma_f32_16x16x32_bf16(a0, b0, acc, 0, 0, 0);
            acc = __builtin_amdgcn_mfma_f32_16x16x32_bf16(a1, b1, acc, 0, 0, 0);
            #pragma unroll
            for (int r = 0; r < 4; ++r) {
                const int o = o0 + quad * 4 + r;
                outb[(size_t)o * HWc + rr * Wc + w0 + n] = acc[r];
            }
        }
    }
}

extern "C" void kernel_launch(void* const* d_in, const int* in_sizes, int n_in,
                              void* d_out, int out_size, void* d_ws, size_t ws_size,
                              hipStream_t stream) {
    const float* x    = (const float*)d_in[0];
    const float* core = (const float*)d_in[1];
    const float* peri = (const float*)d_in[2];
    const float* thr  = (const float*)d_in[3];
    const float* scl  = (const float*)d_in[4];
    float* out = (float*)d_out;

    spconv_kernel<<<dim3(Bc * Hc / 2), dim3(512), 0, stream>>>(
        x, core, peri, thr, scl, out);
}